// Round 12
// baseline (714.861 us; speedup 1.0000x reference)
//
#include <hip/hip_runtime.h>
#include <hip/hip_bf16.h>
#include <math.h>

// ---------------------------------------------------------------------------
// ClusteringModule: e = (z@W1+b1)@W2+b2 ; s = rownorm(1/(1+||e-c||)) ; c=argmax
// Round 15: occupancy attack. GEMM1 keeps r3's proven dbuf loop but stages
// only Ah/Al/Bh in LDS (48KB dbuf -> 3 blocks/CU = 6 waves/SIMD); Bl's 4
// fragments per wave load direct global->VGPR at loop-top (issued BEFORE the
// next-tile stage, so the compiler's bl-wait leaves the prefetch in flight).
// Only 1/4 of operands are direct (vs r6's all-B-direct failure), consumed in
// pass 2 with a full pass-1 of MFMA to hide L2 latency. K-split-6 (grid 768),
// head NKS=6. split_zw unchanged. Numerics identical (absmax 0.015625).
// ---------------------------------------------------------------------------

typedef __bf16 bf16x8 __attribute__((ext_vector_type(8)));
typedef float  f32x4  __attribute__((ext_vector_type(4)));
typedef unsigned short ushort8 __attribute__((ext_vector_type(8)));

#define MROWS 2048
#define KDIM  12000
#define N1    1024
#define N2    64
#define NCL   100

constexpr int KT = 375;          // k-tiles of 32
constexpr int MT = 16;           // m-tiles of 128
constexpr int NT = 8;            // n-tiles of 128
constexpr int TILE_E = 4096;     // 128x32 bf16 elems per tile (8192 B)
constexpr long long AE = (long long)MT * KT * TILE_E;
constexpr long long BE = (long long)NT * KT * TILE_E;
constexpr int NKS = 6;           // K-split slices
constexpr int QS  = 63;          // k-steps per slice (last: 60)

__device__ __forceinline__ unsigned short f2bf(float f) {
  unsigned int u = __float_as_uint(f);
  return (unsigned short)((u + 0x7FFFu + ((u >> 16) & 1u)) >> 16);   // RNE
}
__device__ __forceinline__ float bf2f(unsigned short h) {
  return __uint_as_float(((unsigned int)h) << 16);
}

__device__ __forceinline__ void gl_lds16(const unsigned short* g, unsigned short* l) {
  __builtin_amdgcn_global_load_lds((const __attribute__((address_space(1))) void*)g,
                                   (__attribute__((address_space(3))) void*)l, 16, 0, 0);
}

// ------------- fused pre-split: z -> Ah/Al  and  W1 -> Bh/Bl ---------------
__global__ __launch_bounds__(256)
void split_zw(const float* __restrict__ z, const float* __restrict__ W1,
              unsigned short* __restrict__ Ah, unsigned short* __restrict__ Al,
              unsigned short* __restrict__ Bh, unsigned short* __restrict__ Bl)
{
  __shared__ float tile[32][129];          // W1-path only (16.5 KB)
  const int t  = threadIdx.x;
  const int kt = blockIdx.x;

  if (blockIdx.y < MT) {
    // ---------------- z path ----------------
    const int mt = blockIdx.y;
    const long long tb = (long long)(mt * KT + kt) * TILE_E;
#pragma unroll
    for (int i = 0; i < 2; ++i) {
      const int idx = i * 256 + t;           // 0..511
      const int r   = idx >> 2;              // 0..127
      const int k16 = idx & 3;               // 0..3
      const float* src = z + (long long)(mt * 128 + r) * KDIM + kt * 32 + k16 * 8;
      const float4 v0 = *(const float4*)src;
      const float4 v1 = *(const float4*)(src + 4);
      const float vv[8] = {v0.x, v0.y, v0.z, v0.w, v1.x, v1.y, v1.z, v1.w};
      ushort8 h, l;
#pragma unroll
      for (int j = 0; j < 8; ++j) {
        const unsigned short hs = f2bf(vv[j]);
        h[j] = hs; l[j] = f2bf(vv[j] - bf2f(hs));
      }
      const long long o = tb + (long long)(k16 * 128 + r) * 8;
      *(ushort8*)&Ah[o] = h;
      *(ushort8*)&Al[o] = l;
    }
  } else {
    // ---------------- W1 path ----------------
    const int nt = blockIdx.y - MT;
    const float* src = W1 + (long long)(kt * 32) * N1 + nt * 128;
#pragma unroll
    for (int i = 0; i < 4; ++i) {
      const int idx = i * 256 + t, r = idx >> 5, c4 = idx & 31;
      const float4 v = *(const float4*)(src + (long long)r * N1 + c4 * 4);
      tile[r][c4 * 4 + 0] = v.x; tile[r][c4 * 4 + 1] = v.y;
      tile[r][c4 * 4 + 2] = v.z; tile[r][c4 * 4 + 3] = v.w;
    }
    __syncthreads();
    const long long tb = (long long)(nt * KT + kt) * TILE_E;
#pragma unroll
    for (int i = 0; i < 2; ++i) {
      const int q = i * 256 + t, k16 = q >> 7, col = q & 127;
      ushort8 h, l;
#pragma unroll
      for (int j = 0; j < 8; ++j) {
        const float f = tile[k16 * 8 + j][col];
        const unsigned short hs = f2bf(f);
        h[j] = hs; l[j] = f2bf(f - bf2f(hs));
      }
      *(ushort8*)&Bh[tb + q * 8] = h;
      *(ushort8*)&Bl[tb + q * 8] = l;
    }
  }
}

// ----------------------- GEMM1: split-3 bf16 MFMA ---------------------------
// 128x128 tile, BK=32, 8 waves x (32x64), K-split-6 -> 768 blocks of 512 thr.
// Ah/Al/Bh staged in 48KB LDS dbuf (global_load_lds); Bl direct->VGPR.
// 3 blocks/CU = 24 waves/CU = 6 waves/SIMD.
__global__ __launch_bounds__(512, 6)
void gemm_split3(const unsigned short* __restrict__ Ah, const unsigned short* __restrict__ Al,
                 const unsigned short* __restrict__ Bh, const unsigned short* __restrict__ Bl,
                 const float* __restrict__ b1, float* __restrict__ e1p)
{
  __shared__ unsigned short lds[2][3][TILE_E];   // 48 KB
  const int t = threadIdx.x, lane = t & 63, w = t >> 6;   // w: 0..7
  const int wr = w >> 1, wc = w & 1;                      // wave tile: 32x64
  const int bid = blockIdx.x;
  const int wg = (bid & 7) * 96 + (bid >> 3);    // XCD chunked swizzle, 768%8==0
  const int ks = wg >> 7;                        // 0..5 (128 blocks per slice)
  const int mt = (wg >> 3) & 15;
  const int nt = wg & 7;
  const int s0 = ks * QS;
  const int nst = min(QS, KT - s0);              // 63 x5, 60 last

  const unsigned short* ga0 = Ah + (long long)(mt * KT + s0) * TILE_E;
  const unsigned short* ga1 = Al + (long long)(mt * KT + s0) * TILE_E;
  const unsigned short* ga2 = Bh + (long long)(nt * KT + s0) * TILE_E;
  const unsigned short* gbl = Bl + (long long)(nt * KT + s0) * TILE_E;

  auto stage = [&](int buf, int s) {   // 512 thr x 16B = 8KB = one array each
    const long long so = (long long)s * TILE_E + t * 8;
    gl_lds16(ga0 + so, &lds[buf][0][t * 8]);
    gl_lds16(ga1 + so, &lds[buf][1][t * 8]);
    gl_lds16(ga2 + so, &lds[buf][2][t * 8]);
  };

  f32x4 acc[2][4] = {};
  const int fr = lane & 15, k16 = lane >> 4;

  // per-lane fragment offsets (shorts), step-invariant
  int offA[2], offB[4];
#pragma unroll
  for (int mf = 0; mf < 2; ++mf)
    offA[mf] = k16 * 1024 + (wr * 32 + mf * 16 + fr) * 8;
#pragma unroll
  for (int nf = 0; nf < 4; ++nf)
    offB[nf] = k16 * 1024 + (wc * 64 + nf * 16 + fr) * 8;

  stage(0, 0);
  __syncthreads();
  int buf = 0;
  for (int s = 0; s < nst; ++s) {
    // Bl fragments direct from global, issued FIRST (FIFO vmcnt: the wait for
    // these does not drain the stage batch issued after them).
    bf16x8 bl[4];
    {
      const unsigned short* p = gbl + (long long)s * TILE_E;
#pragma unroll
      for (int nf = 0; nf < 4; ++nf) bl[nf] = *(const bf16x8*)(p + offB[nf]);
    }
    if (s + 1 < nst) stage(buf ^ 1, s + 1);

    bf16x8 ah[2], al[2], bh[4];
#pragma unroll
    for (int mf = 0; mf < 2; ++mf) {
      ah[mf] = *(const bf16x8*)&lds[buf][0][offA[mf]];
      al[mf] = *(const bf16x8*)&lds[buf][1][offA[mf]];
    }
#pragma unroll
    for (int nf = 0; nf < 4; ++nf)
      bh[nf] = *(const bf16x8*)&lds[buf][2][offB[nf]];

    __builtin_amdgcn_s_setprio(1);
    // pass 1: ah x bh (LDS only — covers Bl's L2 latency)
#pragma unroll
    for (int mf = 0; mf < 2; ++mf)
#pragma unroll
      for (int nf = 0; nf < 4; ++nf)
        acc[mf][nf] = __builtin_amdgcn_mfma_f32_16x16x32_bf16(ah[mf], bh[nf], acc[mf][nf], 0, 0, 0);
    // pass 2: ah x bl (direct-loaded operand)
#pragma unroll
    for (int mf = 0; mf < 2; ++mf)
#pragma unroll
      for (int nf = 0; nf < 4; ++nf)
        acc[mf][nf] = __builtin_amdgcn_mfma_f32_16x16x32_bf16(ah[mf], bl[nf], acc[mf][nf], 0, 0, 0);
    // pass 3: al x bh
#pragma unroll
    for (int mf = 0; mf < 2; ++mf)
#pragma unroll
      for (int nf = 0; nf < 4; ++nf)
        acc[mf][nf] = __builtin_amdgcn_mfma_f32_16x16x32_bf16(al[mf], bh[nf], acc[mf][nf], 0, 0, 0);
    __builtin_amdgcn_s_setprio(0);
    __syncthreads();
    buf ^= 1;
  }

  // Epilogue: 16x16 C/D layout col=lane&15, row=(lane>>4)*4+reg (r3-verified)
  float* eo = e1p + (long long)ks * MROWS * N1;
#pragma unroll
  for (int mf = 0; mf < 2; ++mf) {
    const int r0 = mt * 128 + wr * 32 + mf * 16 + ((lane >> 4) << 2);
#pragma unroll
    for (int nf = 0; nf < 4; ++nf) {
      const int col = nt * 128 + wc * 64 + nf * 16 + (lane & 15);
      const float bias = (ks == 0) ? b1[col] : 0.0f;
#pragma unroll
      for (int r = 0; r < 4; ++r)
        eo[(long long)(r0 + r) * N1 + col] = acc[mf][nf][r] + bias;
    }
  }
}

// ------------------------ GEMM2 + distances + argmax ------------------------
// r7 head: cooperative LDS reduction of NKS=6 partials (compile-time
// unrolled, coalesced f32x4), GEMM2 from LDS broadcast, distances + argmax.
constexpr int RPB = 8;

__global__ __launch_bounds__(256, 2)
void head_kernel(const float* __restrict__ e1, const float* __restrict__ W2,
                 const float* __restrict__ b2, const float* __restrict__ cents,
                 float* __restrict__ eOut, float* __restrict__ sOut,
                 float* __restrict__ cOut)
{
  __shared__ float e_red[RPB][N1];        // 32 KB: reduced e1 rows
  __shared__ float cent_s[NCL * 65];      // 26 KB
  __shared__ float e_s[RPB][N2 + 4];
  const int t = threadIdx.x;
  const int r0 = blockIdx.x * RPB;
  constexpr long long PS = (long long)MROWS * N1;

  for (int i = t; i < NCL * N2; i += 256) {
    const int c = i >> 6, d = i & 63;
    cent_s[c * 65 + d] = cents[i];
  }

  // phase 1: reduce NKS partials into e_red (coalesced 1KB/wave loads)
#pragma unroll
  for (int v = 0; v < 8; ++v) {
    const int idx = v * 256 + t;          // 0..2047
    const int row = idx >> 8;             // 0..7
    const int c4  = idx & 255;            // f32x4 slot within row
    const float* src = e1 + (long long)(r0 + row) * N1 + c4 * 4;
    f32x4 x = *(const f32x4*)src;
#pragma unroll
    for (int p = 1; p < NKS; ++p) x += *(const f32x4*)(src + (long long)p * PS);
    *(f32x4*)&e_red[row][c4 * 4] = x;
  }
  __syncthreads();

  // phase 2: GEMM2 from LDS (wave-uniform broadcast reads, conflict-free)
  const int n = t & 63;
  const int rq = t >> 6;
  float acc0 = 0.f, acc1 = 0.f;
  for (int k = 0; k < N1; k += 4) {
    const f32x4 x0 = *(const f32x4*)&e_red[rq][k];
    const f32x4 x1 = *(const f32x4*)&e_red[rq + 4][k];
    const float w0 = W2[(k + 0) * N2 + n];
    const float w1 = W2[(k + 1) * N2 + n];
    const float w2 = W2[(k + 2) * N2 + n];
    const float w3 = W2[(k + 3) * N2 + n];
    acc0 = fmaf(x0[0], w0, acc0); acc0 = fmaf(x0[1], w1, acc0);
    acc0 = fmaf(x0[2], w2, acc0); acc0 = fmaf(x0[3], w3, acc0);
    acc1 = fmaf(x1[0], w0, acc1); acc1 = fmaf(x1[1], w1, acc1);
    acc1 = fmaf(x1[2], w2, acc1); acc1 = fmaf(x1[3], w3, acc1);
  }
  acc0 += b2[n]; acc1 += b2[n];
  eOut[(long long)(r0 + rq) * N2 + n]     = acc0;
  eOut[(long long)(r0 + rq + 4) * N2 + n] = acc1;
  e_s[rq][n]     = acc0;
  e_s[rq + 4][n] = acc1;
  __syncthreads();

  // phase 3: distances + row-normalize + argmax
  const int row = t >> 5;
  const int ci  = t & 31;
  float sum = 0.f, bestv = -1.f;
  int bestc = 0;
  float sv[4] = {0.f, 0.f, 0.f, 0.f};
#pragma unroll
  for (int j = 0; j < 4; ++j) {
    const int c = ci + 32 * j;
    if (c < NCL) {
      float d2 = 0.f;
#pragma unroll 8
      for (int d = 0; d < N2; ++d) {
        const float diff = e_s[row][d] - cent_s[c * 65 + d];
        d2 = fmaf(diff, diff, d2);
      }
      const float su = 1.0f / (1.0f + sqrtf(d2));
      sv[j] = su; sum += su;
      if (su > bestv) { bestv = su; bestc = c; }
    }
  }
#pragma unroll
  for (int off = 1; off < 32; off <<= 1) {
    sum += __shfl_xor(sum, off);
    const float ov = __shfl_xor(bestv, off);
    const int   oc = __shfl_xor(bestc, off);
    if (ov > bestv || (ov == bestv && oc < bestc)) { bestv = ov; bestc = oc; }
  }
  const float inv = 1.0f / sum;
#pragma unroll
  for (int j = 0; j < 4; ++j) {
    const int c = ci + 32 * j;
    if (c < NCL) sOut[(long long)(r0 + row) * NCL + c] = sv[j] * inv;
  }
  if (ci == 0) cOut[r0 + row] = (float)bestc;
}

// --------------------------------- launch -----------------------------------
extern "C" void kernel_launch(void* const* d_in, const int* in_sizes, int n_in,
                              void* d_out, int out_size, void* d_ws, size_t ws_size,
                              hipStream_t stream)
{
  const float* z     = (const float*)d_in[0];
  const float* W1    = (const float*)d_in[1];
  const float* b1    = (const float*)d_in[2];
  const float* W2    = (const float*)d_in[3];
  const float* b2    = (const float*)d_in[4];
  const float* cents = (const float*)d_in[5];
  float* out  = (float*)d_out;
  float* eOut = out;
  float* sOut = out + MROWS * N2;
  float* cOut = out + MROWS * N2 + MROWS * NCL;

  unsigned short* Ah = (unsigned short*)d_ws;
  unsigned short* Al = Ah + AE;
  unsigned short* Bh = Al + AE;
  unsigned short* Bl = Bh + BE;
  float* e1p = (float*)(Bl + BE);   // 6 partials = 48 MB

  split_zw<<<dim3(KT, MT + NT), 256, 0, stream>>>(z, W1, Ah, Al, Bh, Bl);
  gemm_split3<<<NKS * 128, 512, 0, stream>>>(Ah, Al, Bh, Bl, b1, e1p);
  head_kernel<<<MROWS / RPB, 256, 0, stream>>>(e1p, W2, b2, cents, eOut, sOut, cOut);
}

// Round 13
// 194.022 us; speedup vs baseline: 3.6844x; 3.6844x over previous
//
#include <hip/hip_runtime.h>
#include <hip/hip_bf16.h>
#include <math.h>

// ---------------------------------------------------------------------------
// ClusteringModule: e = (z@W1+b1)@W2+b2 ; s = rownorm(1/(1+||e-c||)) ; c=argmax
// Round 16: split_z fused INTO the gemm. A-tiles are staged by loading fp32 z
// directly (32B/lane), converting to bf16 hi/lo in registers, and ds_writing
// into the same dbuf slots split_z used to produce (bit-identical LDS image,
// same single-barrier r3 loop). B keeps global_load_lds staging. Removes
// 196 MB of HBM round-trip (z->Ah/Al->gemm becomes z->gemm) and one launch.
// split_w standalone (W1 only). gemm compute/epilogue + head byte-identical
// to r8/r12 (absmax must stay 0.015625).
// ---------------------------------------------------------------------------

typedef __bf16 bf16x8 __attribute__((ext_vector_type(8)));
typedef float  f32x4  __attribute__((ext_vector_type(4)));
typedef unsigned short ushort8 __attribute__((ext_vector_type(8)));

#define MROWS 2048
#define KDIM  12000
#define N1    1024
#define N2    64
#define NCL   100

constexpr int KT = 375;          // k-tiles of 32
constexpr int MT = 16;           // m-tiles of 128
constexpr int NT = 8;            // n-tiles of 128
constexpr int TILE_E = 4096;     // 128x32 bf16 elems per tile (8192 B)
constexpr long long BE = (long long)NT * KT * TILE_E;

__device__ __forceinline__ unsigned short f2bf(float f) {
  unsigned int u = __float_as_uint(f);
  return (unsigned short)((u + 0x7FFFu + ((u >> 16) & 1u)) >> 16);   // RNE
}
__device__ __forceinline__ float bf2f(unsigned short h) {
  return __uint_as_float(((unsigned int)h) << 16);
}

__device__ __forceinline__ void gl_lds16(const unsigned short* g, unsigned short* l) {
  __builtin_amdgcn_global_load_lds((const __attribute__((address_space(1))) void*)g,
                                   (__attribute__((address_space(3))) void*)l, 16, 0, 0);
}

// --------------------- pre-split: W1 -> Bh/Bl (transposed) ------------------
__global__ __launch_bounds__(256) void split_w(const float* __restrict__ W1,
                                               unsigned short* __restrict__ Bh,
                                               unsigned short* __restrict__ Bl) {
  __shared__ float tile[32][129];
  const int t = threadIdx.x;
  const int kt = blockIdx.x, nt = blockIdx.y;
  const float* src = W1 + (long long)(kt * 32) * N1 + nt * 128;
#pragma unroll
  for (int i = 0; i < 4; ++i) {
    const int idx = i * 256 + t, r = idx >> 5, c4 = idx & 31;
    const float4 v = *(const float4*)(src + (long long)r * N1 + c4 * 4);
    tile[r][c4 * 4 + 0] = v.x; tile[r][c4 * 4 + 1] = v.y;
    tile[r][c4 * 4 + 2] = v.z; tile[r][c4 * 4 + 3] = v.w;
  }
  __syncthreads();
  const long long tb = (long long)(nt * KT + kt) * TILE_E;
#pragma unroll
  for (int i = 0; i < 2; ++i) {
    const int q = i * 256 + t, k16 = q >> 7, col = q & 127;
    ushort8 h, l;
#pragma unroll
    for (int j = 0; j < 8; ++j) {
      const float f = tile[k16 * 8 + j][col];
      const unsigned short hs = f2bf(f);
      h[j] = hs; l[j] = f2bf(f - bf2f(hs));
    }
    *(ushort8*)&Bh[tb + q * 8] = h;
    *(ushort8*)&Bl[tb + q * 8] = l;
  }
}

// ------------------ GEMM1: fused z-split + split-3 bf16 MFMA ----------------
// 128x128 tile, BK=32, 8 waves x (32x64), K-split-4 -> 512 blocks of 512 thr.
// A staged from fp32 z via reg-convert + ds_write (bit-identical to split_z's
// output); B staged via global_load_lds. 64KB dbuf, 2 blocks/CU, 4 waves/SIMD.
__global__ __launch_bounds__(512, 4)
void gemm_fz(const float* __restrict__ z,
             const unsigned short* __restrict__ Bh, const unsigned short* __restrict__ Bl,
             const float* __restrict__ b1, float* __restrict__ e1p)
{
  __shared__ unsigned short lds[2][4][TILE_E];   // 64 KB: Ah, Al, Bh, Bl
  const int t = threadIdx.x, lane = t & 63, w = t >> 6;   // w: 0..7
  const int wr = w >> 1, wc = w & 1;                      // wave tile: 32x64
  const int bid = blockIdx.x;
  const int wg = ((bid & 7) << 6) | (bid >> 3);  // XCD chunked swizzle, 512%8==0
  const int ks = wg >> 7;
  const int mt = (wg >> 3) & 15;
  const int nt = wg & 7;
  const int s0 = ks * 94;
  const int nst = (ks == 3) ? 93 : 94;

  // staging geometry: thread t owns z row r_st, k-octet k16_st of each tile
  const int r_st   = t >> 2;             // 0..127
  const int k16_st = t & 3;              // 0..3
  const float* gz = z + (long long)(mt * 128 + r_st) * KDIM + s0 * 32 + k16_st * 8;
  const int lds_off = (k16_st * 128 + r_st) * 8;   // shorts; == k16*1024 + r*8

  const unsigned short* gb2 = Bh + (long long)(nt * KT + s0) * TILE_E;
  const unsigned short* gb3 = Bl + (long long)(nt * KT + s0) * TILE_E;

  auto stageB = [&](int buf, int s) {
    const long long so = (long long)s * TILE_E + t * 8;
    gl_lds16(gb2 + so, &lds[buf][2][t * 8]);
    gl_lds16(gb3 + so, &lds[buf][3][t * 8]);
  };
  auto writeA = [&](int buf, const float4& v0, const float4& v1) {
    const float vv[8] = {v0.x, v0.y, v0.z, v0.w, v1.x, v1.y, v1.z, v1.w};
    ushort8 h, l;
#pragma unroll
    for (int j = 0; j < 8; ++j) {
      const unsigned short hs = f2bf(vv[j]);
      h[j] = hs; l[j] = f2bf(vv[j] - bf2f(hs));
    }
    *(ushort8*)&lds[buf][0][lds_off] = h;
    *(ushort8*)&lds[buf][1][lds_off] = l;
  };

  f32x4 acc[2][4] = {};
  const int fr = lane & 15, k16 = lane >> 4;

  // prologue: stage tile 0
  {
    const float4 v0 = *(const float4*)gz;
    const float4 v1 = *(const float4*)(gz + 4);
    stageB(0, 0);
    writeA(0, v0, v1);
  }
  __syncthreads();
  int buf = 0;
  for (int s = 0; s < nst; ++s) {
    float4 n0, n1;
    const bool pre = (s + 1 < nst);
    if (pre) {
      const float* p = gz + (long long)(s + 1) * 32;
      n0 = *(const float4*)p;            // z loads issued FIRST (FIFO vmcnt:
      n1 = *(const float4*)(p + 4);      //  their wait leaves B gl_lds in flight)
      stageB(buf ^ 1, s + 1);
    }

    bf16x8 ah[2], al[2], bh[4], bl[4];
#pragma unroll
    for (int mf = 0; mf < 2; ++mf) {
      const int row = wr * 32 + mf * 16 + fr;
      ah[mf] = *(const bf16x8*)&lds[buf][0][k16 * 1024 + row * 8];
      al[mf] = *(const bf16x8*)&lds[buf][1][k16 * 1024 + row * 8];
    }
#pragma unroll
    for (int nf = 0; nf < 4; ++nf) {
      const int col = wc * 64 + nf * 16 + fr;
      bh[nf] = *(const bf16x8*)&lds[buf][2][k16 * 1024 + col * 8];
      bl[nf] = *(const bf16x8*)&lds[buf][3][k16 * 1024 + col * 8];
    }
    __builtin_amdgcn_s_setprio(1);
#pragma unroll
    for (int mf = 0; mf < 2; ++mf)
#pragma unroll
      for (int nf = 0; nf < 4; ++nf)
        acc[mf][nf] = __builtin_amdgcn_mfma_f32_16x16x32_bf16(ah[mf], bh[nf], acc[mf][nf], 0, 0, 0);
#pragma unroll
    for (int mf = 0; mf < 2; ++mf)
#pragma unroll
      for (int nf = 0; nf < 4; ++nf)
        acc[mf][nf] = __builtin_amdgcn_mfma_f32_16x16x32_bf16(ah[mf], bl[nf], acc[mf][nf], 0, 0, 0);
#pragma unroll
    for (int mf = 0; mf < 2; ++mf)
#pragma unroll
      for (int nf = 0; nf < 4; ++nf)
        acc[mf][nf] = __builtin_amdgcn_mfma_f32_16x16x32_bf16(al[mf], bh[nf], acc[mf][nf], 0, 0, 0);
    __builtin_amdgcn_s_setprio(0);

    if (pre) writeA(buf ^ 1, n0, n1);    // convert lands under/after compute
    __syncthreads();                     // drains vmcnt (B) + lgkm (A writes)
    buf ^= 1;
  }

  // Epilogue: 16x16 C/D layout col=lane&15, row=(lane>>4)*4+reg (r3-verified)
  float* eo = e1p + (long long)ks * MROWS * N1;
#pragma unroll
  for (int mf = 0; mf < 2; ++mf) {
    const int r0 = mt * 128 + wr * 32 + mf * 16 + ((lane >> 4) << 2);
#pragma unroll
    for (int nf = 0; nf < 4; ++nf) {
      const int col = nt * 128 + wc * 64 + nf * 16 + (lane & 15);
      const float bias = (ks == 0) ? b1[col] : 0.0f;
#pragma unroll
      for (int r = 0; r < 4; ++r)
        eo[(long long)(r0 + r) * N1 + col] = acc[mf][nf][r] + bias;
    }
  }
}

// ------------------------ GEMM2 + distances + argmax ------------------------
// r7/r8 head: cooperative LDS reduction of NKS=4 partials, GEMM2 from LDS
// broadcast, distances + argmax.
constexpr int RPB = 8;
constexpr int NKS = 4;

__global__ __launch_bounds__(256, 2)
void head_kernel(const float* __restrict__ e1, const float* __restrict__ W2,
                 const float* __restrict__ b2, const float* __restrict__ cents,
                 float* __restrict__ eOut, float* __restrict__ sOut,
                 float* __restrict__ cOut)
{
  __shared__ float e_red[RPB][N1];        // 32 KB: reduced e1 rows
  __shared__ float cent_s[NCL * 65];      // 26 KB
  __shared__ float e_s[RPB][N2 + 4];
  const int t = threadIdx.x;
  const int r0 = blockIdx.x * RPB;
  constexpr long long PS = (long long)MROWS * N1;

  for (int i = t; i < NCL * N2; i += 256) {
    const int c = i >> 6, d = i & 63;
    cent_s[c * 65 + d] = cents[i];
  }

  // phase 1: reduce NKS partials into e_red (coalesced 1KB/wave loads)
#pragma unroll
  for (int v = 0; v < 8; ++v) {
    const int idx = v * 256 + t;          // 0..2047
    const int row = idx >> 8;             // 0..7
    const int c4  = idx & 255;            // f32x4 slot within row
    const float* src = e1 + (long long)(r0 + row) * N1 + c4 * 4;
    f32x4 x = *(const f32x4*)src;
#pragma unroll
    for (int p = 1; p < NKS; ++p) x += *(const f32x4*)(src + (long long)p * PS);
    *(f32x4*)&e_red[row][c4 * 4] = x;
  }
  __syncthreads();

  // phase 2: GEMM2 from LDS (wave-uniform broadcast reads, conflict-free)
  const int n = t & 63;
  const int rq = t >> 6;
  float acc0 = 0.f, acc1 = 0.f;
  for (int k = 0; k < N1; k += 4) {
    const f32x4 x0 = *(const f32x4*)&e_red[rq][k];
    const f32x4 x1 = *(const f32x4*)&e_red[rq + 4][k];
    const float w0 = W2[(k + 0) * N2 + n];
    const float w1 = W2[(k + 1) * N2 + n];
    const float w2 = W2[(k + 2) * N2 + n];
    const float w3 = W2[(k + 3) * N2 + n];
    acc0 = fmaf(x0[0], w0, acc0); acc0 = fmaf(x0[1], w1, acc0);
    acc0 = fmaf(x0[2], w2, acc0); acc0 = fmaf(x0[3], w3, acc0);
    acc1 = fmaf(x1[0], w0, acc1); acc1 = fmaf(x1[1], w1, acc1);
    acc1 = fmaf(x1[2], w2, acc1); acc1 = fmaf(x1[3], w3, acc1);
  }
  acc0 += b2[n]; acc1 += b2[n];
  eOut[(long long)(r0 + rq) * N2 + n]     = acc0;
  eOut[(long long)(r0 + rq + 4) * N2 + n] = acc1;
  e_s[rq][n]     = acc0;
  e_s[rq + 4][n] = acc1;
  __syncthreads();

  // phase 3: distances + row-normalize + argmax
  const int row = t >> 5;
  const int ci  = t & 31;
  float sum = 0.f, bestv = -1.f;
  int bestc = 0;
  float sv[4] = {0.f, 0.f, 0.f, 0.f};
#pragma unroll
  for (int j = 0; j < 4; ++j) {
    const int c = ci + 32 * j;
    if (c < NCL) {
      float d2 = 0.f;
#pragma unroll 8
      for (int d = 0; d < N2; ++d) {
        const float diff = e_s[row][d] - cent_s[c * 65 + d];
        d2 = fmaf(diff, diff, d2);
      }
      const float su = 1.0f / (1.0f + sqrtf(d2));
      sv[j] = su; sum += su;
      if (su > bestv) { bestv = su; bestc = c; }
    }
  }
#pragma unroll
  for (int off = 1; off < 32; off <<= 1) {
    sum += __shfl_xor(sum, off);
    const float ov = __shfl_xor(bestv, off);
    const int   oc = __shfl_xor(bestc, off);
    if (ov > bestv || (ov == bestv && oc < bestc)) { bestv = ov; bestc = oc; }
  }
  const float inv = 1.0f / sum;
#pragma unroll
  for (int j = 0; j < 4; ++j) {
    const int c = ci + 32 * j;
    if (c < NCL) sOut[(long long)(r0 + row) * NCL + c] = sv[j] * inv;
  }
  if (ci == 0) cOut[r0 + row] = (float)bestc;
}

// --------------------------------- launch -----------------------------------
extern "C" void kernel_launch(void* const* d_in, const int* in_sizes, int n_in,
                              void* d_out, int out_size, void* d_ws, size_t ws_size,
                              hipStream_t stream)
{
  const float* z     = (const float*)d_in[0];
  const float* W1    = (const float*)d_in[1];
  const float* b1    = (const float*)d_in[2];
  const float* W2    = (const float*)d_in[3];
  const float* b2    = (const float*)d_in[4];
  const float* cents = (const float*)d_in[5];
  float* out  = (float*)d_out;
  float* eOut = out;
  float* sOut = out + MROWS * N2;
  float* cOut = out + MROWS * N2 + MROWS * NCL;

  unsigned short* Bh = (unsigned short*)d_ws;
  unsigned short* Bl = Bh + BE;
  float* e1p = (float*)(Bl + BE);

  split_w<<<dim3(KT, NT), 256, 0, stream>>>(W1, Bh, Bl);
  gemm_fz<<<512, 512, 0, stream>>>(z, Bh, Bl, b1, e1p);
  head_kernel<<<MROWS / RPB, 256, 0, stream>>>(e1p, W2, b2, cents, eOut, sOut, cOut);
}

// Round 14
// 184.544 us; speedup vs baseline: 3.8737x; 1.0514x over previous
//
#include <hip/hip_runtime.h>
#include <hip/hip_bf16.h>
#include <math.h>

// ---------------------------------------------------------------------------
// ClusteringModule: e = (z@W1+b1)@W2+b2 ; s = rownorm(1/(1+||e-c||)) ; c=argmax
// Round 17: r16 (fused z-split gemm, 194us total) + bank-conflict fix.
// r16's ds_write_b128 A-staging had lanes 0..3 all hitting bank-slot 0
// (SQ_LDS_BANK_CONFLICT=1.84e7). Fix: size-preserving XOR swizzle on the A
// arrays only — 16B-unit index u=k16*128+r remapped r -> r^(2*k16), applied
// identically at write and fragment-read (bijective per k16 block => bit-
// identical data). B arrays stay linear global_load_lds (rule #21). LDS size
// unchanged (64KB, 2 blocks/CU). split_w / head byte-identical to r16.
// ---------------------------------------------------------------------------

typedef __bf16 bf16x8 __attribute__((ext_vector_type(8)));
typedef float  f32x4  __attribute__((ext_vector_type(4)));
typedef unsigned short ushort8 __attribute__((ext_vector_type(8)));

#define MROWS 2048
#define KDIM  12000
#define N1    1024
#define N2    64
#define NCL   100

constexpr int KT = 375;          // k-tiles of 32
constexpr int MT = 16;           // m-tiles of 128
constexpr int NT = 8;            // n-tiles of 128
constexpr int TILE_E = 4096;     // 128x32 bf16 elems per tile (8192 B)
constexpr long long BE = (long long)NT * KT * TILE_E;

__device__ __forceinline__ unsigned short f2bf(float f) {
  unsigned int u = __float_as_uint(f);
  return (unsigned short)((u + 0x7FFFu + ((u >> 16) & 1u)) >> 16);   // RNE
}
__device__ __forceinline__ float bf2f(unsigned short h) {
  return __uint_as_float(((unsigned int)h) << 16);
}

__device__ __forceinline__ void gl_lds16(const unsigned short* g, unsigned short* l) {
  __builtin_amdgcn_global_load_lds((const __attribute__((address_space(1))) void*)g,
                                   (__attribute__((address_space(3))) void*)l, 16, 0, 0);
}

// --------------------- pre-split: W1 -> Bh/Bl (transposed) ------------------
__global__ __launch_bounds__(256) void split_w(const float* __restrict__ W1,
                                               unsigned short* __restrict__ Bh,
                                               unsigned short* __restrict__ Bl) {
  __shared__ float tile[32][129];
  const int t = threadIdx.x;
  const int kt = blockIdx.x, nt = blockIdx.y;
  const float* src = W1 + (long long)(kt * 32) * N1 + nt * 128;
#pragma unroll
  for (int i = 0; i < 4; ++i) {
    const int idx = i * 256 + t, r = idx >> 5, c4 = idx & 31;
    const float4 v = *(const float4*)(src + (long long)r * N1 + c4 * 4);
    tile[r][c4 * 4 + 0] = v.x; tile[r][c4 * 4 + 1] = v.y;
    tile[r][c4 * 4 + 2] = v.z; tile[r][c4 * 4 + 3] = v.w;
  }
  __syncthreads();
  const long long tb = (long long)(nt * KT + kt) * TILE_E;
#pragma unroll
  for (int i = 0; i < 2; ++i) {
    const int q = i * 256 + t, k16 = q >> 7, col = q & 127;
    ushort8 h, l;
#pragma unroll
    for (int j = 0; j < 8; ++j) {
      const float f = tile[k16 * 8 + j][col];
      const unsigned short hs = f2bf(f);
      h[j] = hs; l[j] = f2bf(f - bf2f(hs));
    }
    *(ushort8*)&Bh[tb + q * 8] = h;
    *(ushort8*)&Bl[tb + q * 8] = l;
  }
}

// ------------------ GEMM1: fused z-split + split-3 bf16 MFMA ----------------
// 128x128 tile, BK=32, 8 waves x (32x64), K-split-4 -> 512 blocks of 512 thr.
// A staged from fp32 z via reg-convert + XOR-swizzled ds_write; B staged via
// global_load_lds (linear). 64KB dbuf, 2 blocks/CU, 4 waves/SIMD.
__global__ __launch_bounds__(512, 4)
void gemm_fz(const float* __restrict__ z,
             const unsigned short* __restrict__ Bh, const unsigned short* __restrict__ Bl,
             const float* __restrict__ b1, float* __restrict__ e1p)
{
  __shared__ unsigned short lds[2][4][TILE_E];   // 64 KB: Ah, Al, Bh, Bl
  const int t = threadIdx.x, lane = t & 63, w = t >> 6;   // w: 0..7
  const int wr = w >> 1, wc = w & 1;                      // wave tile: 32x64
  const int bid = blockIdx.x;
  const int wg = ((bid & 7) << 6) | (bid >> 3);  // XCD chunked swizzle, 512%8==0
  const int ks = wg >> 7;
  const int mt = (wg >> 3) & 15;
  const int nt = wg & 7;
  const int s0 = ks * 94;
  const int nst = (ks == 3) ? 93 : 94;

  // staging geometry: thread t owns z row r_st, k-octet k16_st of each tile
  const int r_st   = t >> 2;             // 0..127
  const int k16_st = t & 3;              // 0..3
  const float* gz = z + (long long)(mt * 128 + r_st) * KDIM + s0 * 32 + k16_st * 8;
  // A-LDS swizzle: 16B-unit u = k16*128 + r stored at r^(2*k16) within its
  // k16 block. Write offset (shorts):
  const int lds_off = k16_st * 1024 + (r_st ^ (k16_st << 1)) * 8;

  const unsigned short* gb2 = Bh + (long long)(nt * KT + s0) * TILE_E;
  const unsigned short* gb3 = Bl + (long long)(nt * KT + s0) * TILE_E;

  auto stageB = [&](int buf, int s) {
    const long long so = (long long)s * TILE_E + t * 8;
    gl_lds16(gb2 + so, &lds[buf][2][t * 8]);
    gl_lds16(gb3 + so, &lds[buf][3][t * 8]);
  };
  auto writeA = [&](int buf, const float4& v0, const float4& v1) {
    const float vv[8] = {v0.x, v0.y, v0.z, v0.w, v1.x, v1.y, v1.z, v1.w};
    ushort8 h, l;
#pragma unroll
    for (int j = 0; j < 8; ++j) {
      const unsigned short hs = f2bf(vv[j]);
      h[j] = hs; l[j] = f2bf(vv[j] - bf2f(hs));
    }
    *(ushort8*)&lds[buf][0][lds_off] = h;
    *(ushort8*)&lds[buf][1][lds_off] = l;
  };

  f32x4 acc[2][4] = {};
  const int fr = lane & 15, k16 = lane >> 4;

  // step-invariant fragment read offsets (A uses the same XOR swizzle)
  int offA[2], offB[4];
#pragma unroll
  for (int mf = 0; mf < 2; ++mf) {
    const int row = wr * 32 + mf * 16 + fr;
    offA[mf] = k16 * 1024 + (row ^ (k16 << 1)) * 8;
  }
#pragma unroll
  for (int nf = 0; nf < 4; ++nf)
    offB[nf] = k16 * 1024 + (wc * 64 + nf * 16 + fr) * 8;

  // prologue: stage tile 0
  {
    const float4 v0 = *(const float4*)gz;
    const float4 v1 = *(const float4*)(gz + 4);
    stageB(0, 0);
    writeA(0, v0, v1);
  }
  __syncthreads();
  int buf = 0;
  for (int s = 0; s < nst; ++s) {
    float4 n0, n1;
    const bool pre = (s + 1 < nst);
    if (pre) {
      const float* p = gz + (long long)(s + 1) * 32;
      n0 = *(const float4*)p;            // z loads issued FIRST (FIFO vmcnt:
      n1 = *(const float4*)(p + 4);      //  their wait leaves B gl_lds in flight)
      stageB(buf ^ 1, s + 1);
    }

    bf16x8 ah[2], al[2], bh[4], bl[4];
#pragma unroll
    for (int mf = 0; mf < 2; ++mf) {
      ah[mf] = *(const bf16x8*)&lds[buf][0][offA[mf]];
      al[mf] = *(const bf16x8*)&lds[buf][1][offA[mf]];
    }
#pragma unroll
    for (int nf = 0; nf < 4; ++nf) {
      bh[nf] = *(const bf16x8*)&lds[buf][2][offB[nf]];
      bl[nf] = *(const bf16x8*)&lds[buf][3][offB[nf]];
    }
    __builtin_amdgcn_s_setprio(1);
#pragma unroll
    for (int mf = 0; mf < 2; ++mf)
#pragma unroll
      for (int nf = 0; nf < 4; ++nf)
        acc[mf][nf] = __builtin_amdgcn_mfma_f32_16x16x32_bf16(ah[mf], bh[nf], acc[mf][nf], 0, 0, 0);
#pragma unroll
    for (int mf = 0; mf < 2; ++mf)
#pragma unroll
      for (int nf = 0; nf < 4; ++nf)
        acc[mf][nf] = __builtin_amdgcn_mfma_f32_16x16x32_bf16(ah[mf], bl[nf], acc[mf][nf], 0, 0, 0);
#pragma unroll
    for (int mf = 0; mf < 2; ++mf)
#pragma unroll
      for (int nf = 0; nf < 4; ++nf)
        acc[mf][nf] = __builtin_amdgcn_mfma_f32_16x16x32_bf16(al[mf], bh[nf], acc[mf][nf], 0, 0, 0);
    __builtin_amdgcn_s_setprio(0);

    if (pre) writeA(buf ^ 1, n0, n1);    // convert lands under/after compute
    __syncthreads();                     // drains vmcnt (B) + lgkm (A writes)
    buf ^= 1;
  }

  // Epilogue: 16x16 C/D layout col=lane&15, row=(lane>>4)*4+reg (r3-verified)
  float* eo = e1p + (long long)ks * MROWS * N1;
#pragma unroll
  for (int mf = 0; mf < 2; ++mf) {
    const int r0 = mt * 128 + wr * 32 + mf * 16 + ((lane >> 4) << 2);
#pragma unroll
    for (int nf = 0; nf < 4; ++nf) {
      const int col = nt * 128 + wc * 64 + nf * 16 + (lane & 15);
      const float bias = (ks == 0) ? b1[col] : 0.0f;
#pragma unroll
      for (int r = 0; r < 4; ++r)
        eo[(long long)(r0 + r) * N1 + col] = acc[mf][nf][r] + bias;
    }
  }
}

// ------------------------ GEMM2 + distances + argmax ------------------------
// r7/r8 head: cooperative LDS reduction of NKS=4 partials, GEMM2 from LDS
// broadcast, distances + argmax.
constexpr int RPB = 8;
constexpr int NKS = 4;

__global__ __launch_bounds__(256, 2)
void head_kernel(const float* __restrict__ e1, const float* __restrict__ W2,
                 const float* __restrict__ b2, const float* __restrict__ cents,
                 float* __restrict__ eOut, float* __restrict__ sOut,
                 float* __restrict__ cOut)
{
  __shared__ float e_red[RPB][N1];        // 32 KB: reduced e1 rows
  __shared__ float cent_s[NCL * 65];      // 26 KB
  __shared__ float e_s[RPB][N2 + 4];
  const int t = threadIdx.x;
  const int r0 = blockIdx.x * RPB;
  constexpr long long PS = (long long)MROWS * N1;

  for (int i = t; i < NCL * N2; i += 256) {
    const int c = i >> 6, d = i & 63;
    cent_s[c * 65 + d] = cents[i];
  }

  // phase 1: reduce NKS partials into e_red (coalesced 1KB/wave loads)
#pragma unroll
  for (int v = 0; v < 8; ++v) {
    const int idx = v * 256 + t;          // 0..2047
    const int row = idx >> 8;             // 0..7
    const int c4  = idx & 255;            // f32x4 slot within row
    const float* src = e1 + (long long)(r0 + row) * N1 + c4 * 4;
    f32x4 x = *(const f32x4*)src;
#pragma unroll
    for (int p = 1; p < NKS; ++p) x += *(const f32x4*)(src + (long long)p * PS);
    *(f32x4*)&e_red[row][c4 * 4] = x;
  }
  __syncthreads();

  // phase 2: GEMM2 from LDS (wave-uniform broadcast reads, conflict-free)
  const int n = t & 63;
  const int rq = t >> 6;
  float acc0 = 0.f, acc1 = 0.f;
  for (int k = 0; k < N1; k += 4) {
    const f32x4 x0 = *(const f32x4*)&e_red[rq][k];
    const f32x4 x1 = *(const f32x4*)&e_red[rq + 4][k];
    const float w0 = W2[(k + 0) * N2 + n];
    const float w1 = W2[(k + 1) * N2 + n];
    const float w2 = W2[(k + 2) * N2 + n];
    const float w3 = W2[(k + 3) * N2 + n];
    acc0 = fmaf(x0[0], w0, acc0); acc0 = fmaf(x0[1], w1, acc0);
    acc0 = fmaf(x0[2], w2, acc0); acc0 = fmaf(x0[3], w3, acc0);
    acc1 = fmaf(x1[0], w0, acc1); acc1 = fmaf(x1[1], w1, acc1);
    acc1 = fmaf(x1[2], w2, acc1); acc1 = fmaf(x1[3], w3, acc1);
  }
  acc0 += b2[n]; acc1 += b2[n];
  eOut[(long long)(r0 + rq) * N2 + n]     = acc0;
  eOut[(long long)(r0 + rq + 4) * N2 + n] = acc1;
  e_s[rq][n]     = acc0;
  e_s[rq + 4][n] = acc1;
  __syncthreads();

  // phase 3: distances + row-normalize + argmax
  const int row = t >> 5;
  const int ci  = t & 31;
  float sum = 0.f, bestv = -1.f;
  int bestc = 0;
  float sv[4] = {0.f, 0.f, 0.f, 0.f};
#pragma unroll
  for (int j = 0; j < 4; ++j) {
    const int c = ci + 32 * j;
    if (c < NCL) {
      float d2 = 0.f;
#pragma unroll 8
      for (int d = 0; d < N2; ++d) {
        const float diff = e_s[row][d] - cent_s[c * 65 + d];
        d2 = fmaf(diff, diff, d2);
      }
      const float su = 1.0f / (1.0f + sqrtf(d2));
      sv[j] = su; sum += su;
      if (su > bestv) { bestv = su; bestc = c; }
    }
  }
#pragma unroll
  for (int off = 1; off < 32; off <<= 1) {
    sum += __shfl_xor(sum, off);
    const float ov = __shfl_xor(bestv, off);
    const int   oc = __shfl_xor(bestc, off);
    if (ov > bestv || (ov == bestv && oc < bestc)) { bestv = ov; bestc = oc; }
  }
  const float inv = 1.0f / sum;
#pragma unroll
  for (int j = 0; j < 4; ++j) {
    const int c = ci + 32 * j;
    if (c < NCL) sOut[(long long)(r0 + row) * NCL + c] = sv[j] * inv;
  }
  if (ci == 0) cOut[r0 + row] = (float)bestc;
}

// --------------------------------- launch -----------------------------------
extern "C" void kernel_launch(void* const* d_in, const int* in_sizes, int n_in,
                              void* d_out, int out_size, void* d_ws, size_t ws_size,
                              hipStream_t stream)
{
  const float* z     = (const float*)d_in[0];
  const float* W1    = (const float*)d_in[1];
  const float* b1    = (const float*)d_in[2];
  const float* W2    = (const float*)d_in[3];
  const float* b2    = (const float*)d_in[4];
  const float* cents = (const float*)d_in[5];
  float* out  = (float*)d_out;
  float* eOut = out;
  float* sOut = out + MROWS * N2;
  float* cOut = out + MROWS * N2 + MROWS * NCL;

  unsigned short* Bh = (unsigned short*)d_ws;
  unsigned short* Bl = Bh + BE;
  float* e1p = (float*)(Bl + BE);

  split_w<<<dim3(KT, NT), 256, 0, stream>>>(W1, Bh, Bl);
  gemm_fz<<<512, 512, 0, stream>>>(z, Bh, Bl, b1, e1p);
  head_kernel<<<MROWS / RPB, 256, 0, stream>>>(e1p, W2, b2, cents, eOut, sOut, cOut);
}

// Round 15
// 175.284 us; speedup vs baseline: 4.0783x; 1.0528x over previous
//
#include <hip/hip_runtime.h>
#include <hip/hip_bf16.h>
#include <math.h>

// ---------------------------------------------------------------------------
// ClusteringModule: e = (z@W1+b1)@W2+b2 ; s = rownorm(1/(1+||e-c||)) ; c=argmax
// Round 18: r17 (fused z-split gemm + XOR-swizzled A staging, 184.5us) with
// the f32->bf16 hi/lo conversion rewritten from manual integer RNE (~12 ops/
// elem) to native __bf16 casts (compiler emits v_cvt_pk_bf16_f32, RNE —
// bit-identical output, ~3 ops/elem). Cuts the staging VALU chain ~4x, which
// r17's counters isolated as the fusion's cost (VALUBusy 37% vs r3's 24%).
// Everything else byte-identical to r17.
// ---------------------------------------------------------------------------

typedef __bf16 bf16x8 __attribute__((ext_vector_type(8)));
typedef float  f32x4  __attribute__((ext_vector_type(4)));
typedef unsigned short ushort8 __attribute__((ext_vector_type(8)));

#define MROWS 2048
#define KDIM  12000
#define N1    1024
#define N2    64
#define NCL   100

constexpr int KT = 375;          // k-tiles of 32
constexpr int MT = 16;           // m-tiles of 128
constexpr int NT = 8;            // n-tiles of 128
constexpr int TILE_E = 4096;     // 128x32 bf16 elems per tile (8192 B)
constexpr long long BE = (long long)NT * KT * TILE_E;

__device__ __forceinline__ unsigned short f2bf(float f) {
  unsigned int u = __float_as_uint(f);
  return (unsigned short)((u + 0x7FFFu + ((u >> 16) & 1u)) >> 16);   // RNE
}
__device__ __forceinline__ float bf2f(unsigned short h) {
  return __uint_as_float(((unsigned int)h) << 16);
}

__device__ __forceinline__ void gl_lds16(const unsigned short* g, unsigned short* l) {
  __builtin_amdgcn_global_load_lds((const __attribute__((address_space(1))) void*)g,
                                   (__attribute__((address_space(3))) void*)l, 16, 0, 0);
}

// --------------------- pre-split: W1 -> Bh/Bl (transposed) ------------------
__global__ __launch_bounds__(256) void split_w(const float* __restrict__ W1,
                                               unsigned short* __restrict__ Bh,
                                               unsigned short* __restrict__ Bl) {
  __shared__ float tile[32][129];
  const int t = threadIdx.x;
  const int kt = blockIdx.x, nt = blockIdx.y;
  const float* src = W1 + (long long)(kt * 32) * N1 + nt * 128;
#pragma unroll
  for (int i = 0; i < 4; ++i) {
    const int idx = i * 256 + t, r = idx >> 5, c4 = idx & 31;
    const float4 v = *(const float4*)(src + (long long)r * N1 + c4 * 4);
    tile[r][c4 * 4 + 0] = v.x; tile[r][c4 * 4 + 1] = v.y;
    tile[r][c4 * 4 + 2] = v.z; tile[r][c4 * 4 + 3] = v.w;
  }
  __syncthreads();
  const long long tb = (long long)(nt * KT + kt) * TILE_E;
#pragma unroll
  for (int i = 0; i < 2; ++i) {
    const int q = i * 256 + t, k16 = q >> 7, col = q & 127;
    ushort8 h, l;
#pragma unroll
    for (int j = 0; j < 8; ++j) {
      const float f = tile[k16 * 8 + j][col];
      const unsigned short hs = f2bf(f);
      h[j] = hs; l[j] = f2bf(f - bf2f(hs));
    }
    *(ushort8*)&Bh[tb + q * 8] = h;
    *(ushort8*)&Bl[tb + q * 8] = l;
  }
}

// ------------------ GEMM1: fused z-split + split-3 bf16 MFMA ----------------
// 128x128 tile, BK=32, 8 waves x (32x64), K-split-4 -> 512 blocks of 512 thr.
// A staged from fp32 z via native __bf16 cvt (hw cvt_pk, RNE) + XOR-swizzled
// ds_write; B staged via global_load_lds (linear). 64KB dbuf, 2 blocks/CU.
__global__ __launch_bounds__(512, 4)
void gemm_fz(const float* __restrict__ z,
             const unsigned short* __restrict__ Bh, const unsigned short* __restrict__ Bl,
             const float* __restrict__ b1, float* __restrict__ e1p)
{
  __shared__ unsigned short lds[2][4][TILE_E];   // 64 KB: Ah, Al, Bh, Bl
  const int t = threadIdx.x, lane = t & 63, w = t >> 6;   // w: 0..7
  const int wr = w >> 1, wc = w & 1;                      // wave tile: 32x64
  const int bid = blockIdx.x;
  const int wg = ((bid & 7) << 6) | (bid >> 3);  // XCD chunked swizzle, 512%8==0
  const int ks = wg >> 7;
  const int mt = (wg >> 3) & 15;
  const int nt = wg & 7;
  const int s0 = ks * 94;
  const int nst = (ks == 3) ? 93 : 94;

  // staging geometry: thread t owns z row r_st, k-octet k16_st of each tile
  const int r_st   = t >> 2;             // 0..127
  const int k16_st = t & 3;              // 0..3
  const float* gz = z + (long long)(mt * 128 + r_st) * KDIM + s0 * 32 + k16_st * 8;
  // A-LDS swizzle (r17-verified, conflict-free): u = k16*128 + r stored at
  // r^(2*k16) within its k16 block. Write offset (shorts):
  const int lds_off = k16_st * 1024 + (r_st ^ (k16_st << 1)) * 8;

  const unsigned short* gb2 = Bh + (long long)(nt * KT + s0) * TILE_E;
  const unsigned short* gb3 = Bl + (long long)(nt * KT + s0) * TILE_E;

  auto stageB = [&](int buf, int s) {
    const long long so = (long long)s * TILE_E + t * 8;
    gl_lds16(gb2 + so, &lds[buf][2][t * 8]);
    gl_lds16(gb3 + so, &lds[buf][3][t * 8]);
  };
  auto writeA = [&](int buf, const float4& v0, const float4& v1) {
    const float vv[8] = {v0.x, v0.y, v0.z, v0.w, v1.x, v1.y, v1.z, v1.w};
    ushort8 h, l;
#pragma unroll
    for (int j = 0; j < 8; ++j) {
      const __bf16 hb = (__bf16)vv[j];          // RNE hw cvt (compiler pairs
      const float  hf = (float)hb;              //  into v_cvt_pk_bf16_f32)
      const __bf16 lb = (__bf16)(vv[j] - hf);
      h[j] = __builtin_bit_cast(unsigned short, hb);
      l[j] = __builtin_bit_cast(unsigned short, lb);
    }
    *(ushort8*)&lds[buf][0][lds_off] = h;
    *(ushort8*)&lds[buf][1][lds_off] = l;
  };

  f32x4 acc[2][4] = {};
  const int fr = lane & 15, k16 = lane >> 4;

  // step-invariant fragment read offsets (A uses the same XOR swizzle)
  int offA[2], offB[4];
#pragma unroll
  for (int mf = 0; mf < 2; ++mf) {
    const int row = wr * 32 + mf * 16 + fr;
    offA[mf] = k16 * 1024 + (row ^ (k16 << 1)) * 8;
  }
#pragma unroll
  for (int nf = 0; nf < 4; ++nf)
    offB[nf] = k16 * 1024 + (wc * 64 + nf * 16 + fr) * 8;

  // prologue: stage tile 0
  {
    const float4 v0 = *(const float4*)gz;
    const float4 v1 = *(const float4*)(gz + 4);
    stageB(0, 0);
    writeA(0, v0, v1);
  }
  __syncthreads();
  int buf = 0;
  for (int s = 0; s < nst; ++s) {
    float4 n0, n1;
    const bool pre = (s + 1 < nst);
    if (pre) {
      const float* p = gz + (long long)(s + 1) * 32;
      n0 = *(const float4*)p;            // z loads issued FIRST (FIFO vmcnt:
      n1 = *(const float4*)(p + 4);      //  their wait leaves B gl_lds in flight)
      stageB(buf ^ 1, s + 1);
    }

    bf16x8 ah[2], al[2], bh[4], bl[4];
#pragma unroll
    for (int mf = 0; mf < 2; ++mf) {
      ah[mf] = *(const bf16x8*)&lds[buf][0][offA[mf]];
      al[mf] = *(const bf16x8*)&lds[buf][1][offA[mf]];
    }
#pragma unroll
    for (int nf = 0; nf < 4; ++nf) {
      bh[nf] = *(const bf16x8*)&lds[buf][2][offB[nf]];
      bl[nf] = *(const bf16x8*)&lds[buf][3][offB[nf]];
    }
    __builtin_amdgcn_s_setprio(1);
#pragma unroll
    for (int mf = 0; mf < 2; ++mf)
#pragma unroll
      for (int nf = 0; nf < 4; ++nf)
        acc[mf][nf] = __builtin_amdgcn_mfma_f32_16x16x32_bf16(ah[mf], bh[nf], acc[mf][nf], 0, 0, 0);
#pragma unroll
    for (int mf = 0; mf < 2; ++mf)
#pragma unroll
      for (int nf = 0; nf < 4; ++nf)
        acc[mf][nf] = __builtin_amdgcn_mfma_f32_16x16x32_bf16(ah[mf], bl[nf], acc[mf][nf], 0, 0, 0);
#pragma unroll
    for (int mf = 0; mf < 2; ++mf)
#pragma unroll
      for (int nf = 0; nf < 4; ++nf)
        acc[mf][nf] = __builtin_amdgcn_mfma_f32_16x16x32_bf16(al[mf], bh[nf], acc[mf][nf], 0, 0, 0);
    __builtin_amdgcn_s_setprio(0);

    if (pre) writeA(buf ^ 1, n0, n1);    // convert lands under/after compute
    __syncthreads();                     // drains vmcnt (B) + lgkm (A writes)
    buf ^= 1;
  }

  // Epilogue: 16x16 C/D layout col=lane&15, row=(lane>>4)*4+reg (r3-verified)
  float* eo = e1p + (long long)ks * MROWS * N1;
#pragma unroll
  for (int mf = 0; mf < 2; ++mf) {
    const int r0 = mt * 128 + wr * 32 + mf * 16 + ((lane >> 4) << 2);
#pragma unroll
    for (int nf = 0; nf < 4; ++nf) {
      const int col = nt * 128 + wc * 64 + nf * 16 + (lane & 15);
      const float bias = (ks == 0) ? b1[col] : 0.0f;
#pragma unroll
      for (int r = 0; r < 4; ++r)
        eo[(long long)(r0 + r) * N1 + col] = acc[mf][nf][r] + bias;
    }
  }
}

// ------------------------ GEMM2 + distances + argmax ------------------------
// r7/r8 head: cooperative LDS reduction of NKS=4 partials, GEMM2 from LDS
// broadcast, distances + argmax.
constexpr int RPB = 8;
constexpr int NKS = 4;

__global__ __launch_bounds__(256, 2)
void head_kernel(const float* __restrict__ e1, const float* __restrict__ W2,
                 const float* __restrict__ b2, const float* __restrict__ cents,
                 float* __restrict__ eOut, float* __restrict__ sOut,
                 float* __restrict__ cOut)
{
  __shared__ float e_red[RPB][N1];        // 32 KB: reduced e1 rows
  __shared__ float cent_s[NCL * 65];      // 26 KB
  __shared__ float e_s[RPB][N2 + 4];
  const int t = threadIdx.x;
  const int r0 = blockIdx.x * RPB;
  constexpr long long PS = (long long)MROWS * N1;

  for (int i = t; i < NCL * N2; i += 256) {
    const int c = i >> 6, d = i & 63;
    cent_s[c * 65 + d] = cents[i];
  }

  // phase 1: reduce NKS partials into e_red (coalesced 1KB/wave loads)
#pragma unroll
  for (int v = 0; v < 8; ++v) {
    const int idx = v * 256 + t;          // 0..2047
    const int row = idx >> 8;             // 0..7
    const int c4  = idx & 255;            // f32x4 slot within row
    const float* src = e1 + (long long)(r0 + row) * N1 + c4 * 4;
    f32x4 x = *(const f32x4*)src;
#pragma unroll
    for (int p = 1; p < NKS; ++p) x += *(const f32x4*)(src + (long long)p * PS);
    *(f32x4*)&e_red[row][c4 * 4] = x;
  }
  __syncthreads();

  // phase 2: GEMM2 from LDS (wave-uniform broadcast reads, conflict-free)
  const int n = t & 63;
  const int rq = t >> 6;
  float acc0 = 0.f, acc1 = 0.f;
  for (int k = 0; k < N1; k += 4) {
    const f32x4 x0 = *(const f32x4*)&e_red[rq][k];
    const f32x4 x1 = *(const f32x4*)&e_red[rq + 4][k];
    const float w0 = W2[(k + 0) * N2 + n];
    const float w1 = W2[(k + 1) * N2 + n];
    const float w2 = W2[(k + 2) * N2 + n];
    const float w3 = W2[(k + 3) * N2 + n];
    acc0 = fmaf(x0[0], w0, acc0); acc0 = fmaf(x0[1], w1, acc0);
    acc0 = fmaf(x0[2], w2, acc0); acc0 = fmaf(x0[3], w3, acc0);
    acc1 = fmaf(x1[0], w0, acc1); acc1 = fmaf(x1[1], w1, acc1);
    acc1 = fmaf(x1[2], w2, acc1); acc1 = fmaf(x1[3], w3, acc1);
  }
  acc0 += b2[n]; acc1 += b2[n];
  eOut[(long long)(r0 + rq) * N2 + n]     = acc0;
  eOut[(long long)(r0 + rq + 4) * N2 + n] = acc1;
  e_s[rq][n]     = acc0;
  e_s[rq + 4][n] = acc1;
  __syncthreads();

  // phase 3: distances + row-normalize + argmax
  const int row = t >> 5;
  const int ci  = t & 31;
  float sum = 0.f, bestv = -1.f;
  int bestc = 0;
  float sv[4] = {0.f, 0.f, 0.f, 0.f};
#pragma unroll
  for (int j = 0; j < 4; ++j) {
    const int c = ci + 32 * j;
    if (c < NCL) {
      float d2 = 0.f;
#pragma unroll 8
      for (int d = 0; d < N2; ++d) {
        const float diff = e_s[row][d] - cent_s[c * 65 + d];
        d2 = fmaf(diff, diff, d2);
      }
      const float su = 1.0f / (1.0f + sqrtf(d2));
      sv[j] = su; sum += su;
      if (su > bestv) { bestv = su; bestc = c; }
    }
  }
#pragma unroll
  for (int off = 1; off < 32; off <<= 1) {
    sum += __shfl_xor(sum, off);
    const float ov = __shfl_xor(bestv, off);
    const int   oc = __shfl_xor(bestc, off);
    if (ov > bestv || (ov == bestv && oc < bestc)) { bestv = ov; bestc = oc; }
  }
  const float inv = 1.0f / sum;
#pragma unroll
  for (int j = 0; j < 4; ++j) {
    const int c = ci + 32 * j;
    if (c < NCL) sOut[(long long)(r0 + row) * NCL + c] = sv[j] * inv;
  }
  if (ci == 0) cOut[r0 + row] = (float)bestc;
}

// --------------------------------- launch -----------------------------------
extern "C" void kernel_launch(void* const* d_in, const int* in_sizes, int n_in,
                              void* d_out, int out_size, void* d_ws, size_t ws_size,
                              hipStream_t stream)
{
  const float* z     = (const float*)d_in[0];
  const float* W1    = (const float*)d_in[1];
  const float* b1    = (const float*)d_in[2];
  const float* W2    = (const float*)d_in[3];
  const float* b2    = (const float*)d_in[4];
  const float* cents = (const float*)d_in[5];
  float* out  = (float*)d_out;
  float* eOut = out;
  float* sOut = out + MROWS * N2;
  float* cOut = out + MROWS * N2 + MROWS * NCL;

  unsigned short* Bh = (unsigned short*)d_ws;
  unsigned short* Bl = Bh + BE;
  float* e1p = (float*)(Bl + BE);

  split_w<<<dim3(KT, NT), 256, 0, stream>>>(W1, Bh, Bl);
  gemm_fz<<<512, 512, 0, stream>>>(z, Bh, Bl, b1, e1p);
  head_kernel<<<MROWS / RPB, 256, 0, stream>>>(e1p, W2, b2, cents, eOut, sOut, cOut);
}